// Round 1
// baseline (254.183 us; speedup 1.0000x reference)
//
#include <hip/hip_runtime.h>

#define PAD 68

// ---------------- K0: inv_diag[n,c,k] = rsqrt(max(|x[n,c,k,k]|, 1e-4)) -------
__global__ __launch_bounds__(256) void k0_invdiag(const float* __restrict__ x,
                                                  float* __restrict__ invd) {
    int t = blockIdx.x * 256 + threadIdx.x;   // [0, 64*64*64)
    int nc = t >> 6, k = t & 63;
    float v = fabsf(x[(size_t)nc * 4096 + (size_t)k * 65]);
    invd[t] = rsqrtf(fmaxf(v, 1e-4f));
}

__device__ __forceinline__ void zero4x4(float (&acc)[4][4]) {
#pragma unroll
    for (int i = 0; i < 4; ++i)
#pragma unroll
        for (int j = 0; j < 4; ++j) acc[i][j] = 0.0f;
}

__device__ __forceinline__ void fma4x4(float (&acc)[4][4], float4 a, float4 b) {
    float av[4] = {a.x, a.y, a.z, a.w};
    float bv[4] = {b.x, b.y, b.z, b.w};
#pragma unroll
    for (int i = 0; i < 4; ++i)
#pragma unroll
        for (int j = 0; j < 4; ++j)
            acc[i][j] = fmaf(av[i], bv[j], acc[i][j]);
}

// ---------------- K1: cov2cor + channel mixing -------------------------------
// Block = (n, i-row). Output: Q/K/V [n, co, i, j] = sum_c Wx[c][co]*cor[n,c,i,j]
__global__ __launch_bounds__(256, 2) void k1_mix(
    const float* __restrict__ x, const float* __restrict__ invd,
    const float* __restrict__ wq, const float* __restrict__ wk,
    const float* __restrict__ wv,
    float* __restrict__ Qo, float* __restrict__ Ko, float* __restrict__ Vo)
{
    __shared__ float cor_s[64][PAD];
    __shared__ float wq_s[64][PAD], wk_s[64][PAD], wv_s[64][PAD];
    const int b = blockIdx.x;          // n*64 + i
    const int n = b >> 6, i = b & 63;
    const int t = threadIdx.x;

#pragma unroll
    for (int rep = 0; rep < 4; ++rep) {
        int f4 = rep * 256 + t;        // 0..1023 float4 slots
        int r = f4 >> 4, c4 = (f4 & 15) * 4;
        *(float4*)&wq_s[r][c4] = *(const float4*)&wq[r * 64 + c4];
        *(float4*)&wk_s[r][c4] = *(const float4*)&wk[r * 64 + c4];
        *(float4*)&wv_s[r][c4] = *(const float4*)&wv[r * 64 + c4];
    }
    const size_t nbase = (size_t)n * 64;
#pragma unroll
    for (int rep = 0; rep < 16; ++rep) {
        int f = rep * 256 + t;         // 0..4095
        int c = f >> 6, j = f & 63;
        float xv = x[((nbase + c) * 64 + i) * 64 + j];
        float ii = invd[(nbase + c) * 64 + i];
        float ij = invd[(nbase + c) * 64 + j];
        float v = xv * ii * ij;
        cor_s[c][j] = fminf(1.0f, fmaxf(-1.0f, v));
    }
    __syncthreads();

    const int tr = t >> 4, tc = t & 15;
    float aq[4][4], ak[4][4], av_[4][4];
    zero4x4(aq); zero4x4(ak); zero4x4(av_);
#pragma unroll 8
    for (int m = 0; m < 64; ++m) {
        float4 bb = *(float4*)&cor_s[m][tc * 4];
        fma4x4(aq,  *(float4*)&wq_s[m][tr * 4], bb);
        fma4x4(ak,  *(float4*)&wk_s[m][tr * 4], bb);
        fma4x4(av_, *(float4*)&wv_s[m][tr * 4], bb);
    }
    const size_t obase = nbase * 4096 + (size_t)i * 64 + (size_t)tc * 4;
#pragma unroll
    for (int di = 0; di < 4; ++di) {
        size_t o = obase + (size_t)(tr * 4 + di) * 4096;
        *(float4*)&Qo[o] = make_float4(aq[di][0],  aq[di][1],  aq[di][2],  aq[di][3]);
        *(float4*)&Ko[o] = make_float4(ak[di][0],  ak[di][1],  ak[di][2],  ak[di][3]);
        *(float4*)&Vo[o] = make_float4(av_[di][0], av_[di][1], av_[di][2], av_[di][3]);
    }
}

// ---------------- K2: per-(n,c) attention chain ------------------------------
// A_pre = K^T Q K ; A = soft_pd_max(A_pre) ; out = x + A V A^T
// All matmuls as C[a][b] = sum_m AT[m][a] * B[m][b]  (k-major reads, natural writes)
__global__ __launch_bounds__(256, 2) void k2_attn(
    const float* __restrict__ x, const float* __restrict__ Qi,
    const float* __restrict__ Ki, const float* __restrict__ Vi,
    float* __restrict__ out)
{
    __shared__ float B0[64][PAD];   // Q  -> At
    __shared__ float B1[64][PAD];   // K
    __shared__ float B2[64][PAD];   // V
    __shared__ float B3[64][PAD];   // T1t -> T2t
    __shared__ float part[16][64];
    __shared__ float invs[64];
    __shared__ float red[4];

    const int t = threadIdx.x;
    const size_t gbase = (size_t)blockIdx.x * 4096;

#pragma unroll
    for (int rep = 0; rep < 4; ++rep) {
        int f4 = rep * 256 + t;
        int r = f4 >> 4, c4 = (f4 & 15) * 4;
        *(float4*)&B0[r][c4] = *(const float4*)&Qi[gbase + r * 64 + c4];
        *(float4*)&B1[r][c4] = *(const float4*)&Ki[gbase + r * 64 + c4];
        *(float4*)&B2[r][c4] = *(const float4*)&Vi[gbase + r * 64 + c4];
    }
    __syncthreads();

    const int tr = t >> 4, tc = t & 15;
    float acc[4][4];

    // M1: T1t = Q^T K   (T1t[a][b] = sum_m Q[m][a]*K[m][b]) -> B3
    zero4x4(acc);
#pragma unroll 8
    for (int m = 0; m < 64; ++m)
        fma4x4(acc, *(float4*)&B0[m][tr * 4], *(float4*)&B1[m][tc * 4]);
#pragma unroll
    for (int di = 0; di < 4; ++di)
        *(float4*)&B3[tr * 4 + di][tc * 4] =
            make_float4(acc[di][0], acc[di][1], acc[di][2], acc[di][3]);
    __syncthreads();

    // M2: Pt = K^T T1t  (Pt[a][b] = sum_m K[m][a]*T1t[m][b]) -- kept in regs
    zero4x4(acc);
#pragma unroll 8
    for (int m = 0; m < 64; ++m)
        fma4x4(acc, *(float4*)&B1[m][tr * 4], *(float4*)&B3[m][tc * 4]);

    // global max over all of Pt
    float lmax = acc[0][0];
#pragma unroll
    for (int i = 0; i < 4; ++i)
#pragma unroll
        for (int j = 0; j < 4; ++j) lmax = fmaxf(lmax, acc[i][j]);
#pragma unroll
    for (int off = 1; off < 64; off <<= 1)
        lmax = fmaxf(lmax, __shfl_xor(lmax, off));
    if ((t & 63) == 0) red[t >> 6] = lmax;
    __syncthreads();
    float mx = fmaxf(fmaxf(red[0], red[1]), fmaxf(red[2], red[3]));

    // e = exp(Pt - mx); column partials (= partial row sums of e in P coords)
    float e[4][4];
    float csum[4] = {0.f, 0.f, 0.f, 0.f};
#pragma unroll
    for (int di = 0; di < 4; ++di)
#pragma unroll
        for (int dj = 0; dj < 4; ++dj) {
            float ev = __expf(acc[di][dj] - mx);
            e[di][dj] = ev;
            csum[dj] += ev;
        }
    *(float4*)&part[tr][tc * 4] = make_float4(csum[0], csum[1], csum[2], csum[3]);
    __syncthreads();

    if (t < 64) {
        float dia = 0.f;
#pragma unroll
        for (int g = 0; g < 16; ++g) dia += part[g][t];
        float tot = dia;
#pragma unroll
        for (int off = 1; off < 64; off <<= 1) tot += __shfl_xor(tot, off);
        dia = fmaxf(dia, tot / 100000.0f);
        dia = fmaxf(dia, 1e-5f);
        invs[t] = rsqrtf(dia);
    }
    __syncthreads();

    // At[a][b] = e[a][b] * invs[a] * invs[b]  -> B0 (Q slot, free since M1)
    {
        float4 ic = *(float4*)&invs[tc * 4];
        float icv[4] = {ic.x, ic.y, ic.z, ic.w};
#pragma unroll
        for (int di = 0; di < 4; ++di) {
            float ir = invs[tr * 4 + di];
            *(float4*)&B0[tr * 4 + di][tc * 4] =
                make_float4(e[di][0] * ir * icv[0], e[di][1] * ir * icv[1],
                            e[di][2] * ir * icv[2], e[di][3] * ir * icv[3]);
        }
    }
    __syncthreads();

    // M3: T2t = (A V)^T  (T2t[a][b] = sum_m V[m][a]*At[m][b]) -> B3
    zero4x4(acc);
#pragma unroll 8
    for (int m = 0; m < 64; ++m)
        fma4x4(acc, *(float4*)&B2[m][tr * 4], *(float4*)&B0[m][tc * 4]);
#pragma unroll
    for (int di = 0; di < 4; ++di)
        *(float4*)&B3[tr * 4 + di][tc * 4] =
            make_float4(acc[di][0], acc[di][1], acc[di][2], acc[di][3]);
    __syncthreads();

    // M4: out[i][j] = x[i][j] + sum_m T2t[m][i]*At[m][j]
    zero4x4(acc);
#pragma unroll 8
    for (int m = 0; m < 64; ++m)
        fma4x4(acc, *(float4*)&B3[m][tr * 4], *(float4*)&B0[m][tc * 4]);
#pragma unroll
    for (int di = 0; di < 4; ++di) {
        size_t o = gbase + (size_t)(tr * 4 + di) * 64 + (size_t)tc * 4;
        float4 xi = *(const float4*)&x[o];
        *(float4*)&out[o] = make_float4(xi.x + acc[di][0], xi.y + acc[di][1],
                                        xi.z + acc[di][2], xi.w + acc[di][3]);
    }
}

// ---------------- launch -----------------------------------------------------
extern "C" void kernel_launch(void* const* d_in, const int* in_sizes, int n_in,
                              void* d_out, int out_size, void* d_ws, size_t ws_size,
                              hipStream_t stream) {
    const float* x  = (const float*)d_in[0];
    const float* wq = (const float*)d_in[1];
    const float* wk = (const float*)d_in[2];
    const float* wv = (const float*)d_in[3];
    float* out = (float*)d_out;

    float* invd = (float*)d_ws;                 // 262,144 floats (1 MB)
    float* K    = invd + 262144;                // 16,777,216 floats (64 MB)
    float* V    = K + 16777216;                 // 16,777,216 floats (64 MB)
    float* Q    = out;                          // reuse d_out as Q scratch

    k0_invdiag<<<1024, 256, 0, stream>>>(x, invd);
    k1_mix<<<4096, 256, 0, stream>>>(x, invd, wq, wk, wv, Q, K, V);
    k2_attn<<<4096, 256, 0, stream>>>(x, Q, K, V, out);
}

// Round 2
// 179.038 us; speedup vs baseline: 1.4197x; 1.4197x over previous
//
#include <hip/hip_runtime.h>

#define PAD 68
#define PITCH 72   // bf16 pitch for MFMA planes: 144 B rows, 16B-aligned, 2-way-max banks

typedef __attribute__((ext_vector_type(8))) short short8v;
typedef __attribute__((ext_vector_type(4))) short short4v;
typedef __attribute__((ext_vector_type(4))) float f32x4;

// ---------------- K0: inv_diag[n,c,k] = rsqrt(max(|x[n,c,k,k]|, 1e-4)) -------
__global__ __launch_bounds__(256) void k0_invdiag(const float* __restrict__ x,
                                                  float* __restrict__ invd) {
    int t = blockIdx.x * 256 + threadIdx.x;   // [0, 64*64*64)
    int nc = t >> 6, k = t & 63;
    float v = fabsf(x[(size_t)nc * 4096 + (size_t)k * 65]);
    invd[t] = rsqrtf(fmaxf(v, 1e-4f));
}

__device__ __forceinline__ void zero4x4(float (&acc)[4][4]) {
#pragma unroll
    for (int i = 0; i < 4; ++i)
#pragma unroll
        for (int j = 0; j < 4; ++j) acc[i][j] = 0.0f;
}

__device__ __forceinline__ void fma4x4(float (&acc)[4][4], float4 a, float4 b) {
    float av[4] = {a.x, a.y, a.z, a.w};
    float bv[4] = {b.x, b.y, b.z, b.w};
#pragma unroll
    for (int i = 0; i < 4; ++i)
#pragma unroll
        for (int j = 0; j < 4; ++j)
            acc[i][j] = fmaf(av[i], bv[j], acc[i][j]);
}

// ---------------- K1: cov2cor + channel mixing (unchanged, fp32 VALU) --------
__global__ __launch_bounds__(256, 2) void k1_mix(
    const float* __restrict__ x, const float* __restrict__ invd,
    const float* __restrict__ wq, const float* __restrict__ wk,
    const float* __restrict__ wv,
    float* __restrict__ Qo, float* __restrict__ Ko, float* __restrict__ Vo)
{
    __shared__ float cor_s[64][PAD];
    __shared__ float wq_s[64][PAD], wk_s[64][PAD], wv_s[64][PAD];
    const int b = blockIdx.x;          // n*64 + i
    const int n = b >> 6, i = b & 63;
    const int t = threadIdx.x;

#pragma unroll
    for (int rep = 0; rep < 4; ++rep) {
        int f4 = rep * 256 + t;
        int r = f4 >> 4, c4 = (f4 & 15) * 4;
        *(float4*)&wq_s[r][c4] = *(const float4*)&wq[r * 64 + c4];
        *(float4*)&wk_s[r][c4] = *(const float4*)&wk[r * 64 + c4];
        *(float4*)&wv_s[r][c4] = *(const float4*)&wv[r * 64 + c4];
    }
    const size_t nbase = (size_t)n * 64;
#pragma unroll
    for (int rep = 0; rep < 16; ++rep) {
        int f = rep * 256 + t;
        int c = f >> 6, j = f & 63;
        float xv = x[((nbase + c) * 64 + i) * 64 + j];
        float ii = invd[(nbase + c) * 64 + i];
        float ij = invd[(nbase + c) * 64 + j];
        float v = xv * ii * ij;
        cor_s[c][j] = fminf(1.0f, fmaxf(-1.0f, v));
    }
    __syncthreads();

    const int tr = t >> 4, tc = t & 15;
    float aq[4][4], ak[4][4], av_[4][4];
    zero4x4(aq); zero4x4(ak); zero4x4(av_);
#pragma unroll 8
    for (int m = 0; m < 64; ++m) {
        float4 bb = *(float4*)&cor_s[m][tc * 4];
        fma4x4(aq,  *(float4*)&wq_s[m][tr * 4], bb);
        fma4x4(ak,  *(float4*)&wk_s[m][tr * 4], bb);
        fma4x4(av_, *(float4*)&wv_s[m][tr * 4], bb);
    }
    const size_t obase = nbase * 4096 + (size_t)i * 64 + (size_t)tc * 4;
#pragma unroll
    for (int di = 0; di < 4; ++di) {
        size_t o = obase + (size_t)(tr * 4 + di) * 4096;
        *(float4*)&Qo[o] = make_float4(aq[di][0],  aq[di][1],  aq[di][2],  aq[di][3]);
        *(float4*)&Ko[o] = make_float4(ak[di][0],  ak[di][1],  ak[di][2],  ak[di][3]);
        *(float4*)&Vo[o] = make_float4(av_[di][0], av_[di][1], av_[di][2], av_[di][3]);
    }
}

// ---------------- bf16 split helpers -----------------------------------------
__device__ __forceinline__ short f2bf(float v) {
    unsigned u = __builtin_bit_cast(unsigned, v);
    unsigned r = (u + 0x7FFFu + ((u >> 16) & 1u)) >> 16;
    return (short)r;
}
__device__ __forceinline__ float bf2f(short s) {
    unsigned u = ((unsigned)(unsigned short)s) << 16;
    return __builtin_bit_cast(float, u);
}

#define MFMA(a, b, c) __builtin_amdgcn_mfma_f32_16x16x32_bf16(a, b, c, 0, 0, 0)

// global fp32 [64][64] -> hi/lo bf16 planes [64][PITCH]
__device__ __forceinline__ void stage_mat(const float* __restrict__ g,
                                          short* ph, short* plo, int t) {
#pragma unroll
    for (int rep = 0; rep < 4; ++rep) {
        int idx = rep * 256 + t;               // 1024 float4 slots
        int row = idx >> 4, c4 = (idx & 15) * 4;
        float4 v = *(const float4*)&g[row * 64 + c4];
        float vv[4] = {v.x, v.y, v.z, v.w};
        short4v h, l;
#pragma unroll
        for (int xx = 0; xx < 4; ++xx) {
            short hb = f2bf(vv[xx]);
            h[xx] = hb;
            l[xx] = f2bf(vv[xx] - bf2f(hb));
        }
        *(short4v*)&ph[row * PITCH + c4]  = h;
        *(short4v*)&plo[row * PITCH + c4] = l;
    }
}

// A/B fragment: lane reads row (rowtile*16 + (l&15)), 8 bf16 at k = kc*32 + (l>>4)*8
__device__ __forceinline__ short8v ldfrag(const short* p, int rowtile, int kc, int l) {
    return *(const short8v*)&p[(rowtile * 16 + (l & 15)) * PITCH + kc * 32 + (l >> 4) * 8];
}

// D = X·Y^T with split-3 (hh + hl + lh); wave w owns D row-tile w, all 4 col-tiles
__device__ __forceinline__ void p3(const short* xh, const short* xl,
                                   const short* yh, const short* yl,
                                   int w, int l, f32x4 (&acc)[4]) {
#pragma unroll
    for (int ct = 0; ct < 4; ++ct) acc[ct] = (f32x4){0.f, 0.f, 0.f, 0.f};
#pragma unroll
    for (int kc = 0; kc < 2; ++kc) {
        short8v aH = ldfrag(xh, w, kc, l);
        short8v aL = ldfrag(xl, w, kc, l);
#pragma unroll
        for (int ct = 0; ct < 4; ++ct) {
            short8v bH = ldfrag(yh, ct, kc, l);
            short8v bL = ldfrag(yl, ct, kc, l);
            acc[ct] = MFMA(aH, bH, acc[ct]);
            acc[ct] = MFMA(aH, bL, acc[ct]);
            acc[ct] = MFMA(aL, bH, acc[ct]);
        }
    }
}

// pack-store D transposed with hi/lo split: z[n][m] = D[m][n]
__device__ __forceinline__ void pack_store(const f32x4 (&acc)[4],
                                           short* zh, short* zl, int w, int l) {
    int m0 = w * 16 + (l >> 4) * 4;
#pragma unroll
    for (int ct = 0; ct < 4; ++ct) {
        int n = ct * 16 + (l & 15);
        short4v h, lo;
#pragma unroll
        for (int r = 0; r < 4; ++r) {
            float v = acc[ct][r];
            short hb = f2bf(v);
            h[r]  = hb;
            lo[r] = f2bf(v - bf2f(hb));
        }
        *(short4v*)&zh[n * PITCH + m0] = h;
        *(short4v*)&zl[n * PITCH + m0] = lo;
    }
}

// exact transpose via identity-MFMA: dst[j][i] = src[i][j]; wave w does src rows [16w,16w+16)
__device__ __forceinline__ void idtrans(const short* src, short* dst, int w, int l) {
    int m0 = w * 16 + (l >> 4) * 4;
#pragma unroll
    for (int s = 0; s < 4; ++s) {
        short8v a = ldfrag(src, w, s >> 1, l);
        short8v b;
#pragma unroll
        for (int j = 0; j < 8; ++j)
            b[j] = (8 * (l >> 4) + j == (l & 15) + 16 * (s & 1)) ? (short)0x3F80 : (short)0;
        f32x4 d = MFMA(a, b, ((f32x4){0.f, 0.f, 0.f, 0.f}));
        short4v h;
#pragma unroll
        for (int r = 0; r < 4; ++r) h[r] = f2bf(d[r]);   // exact (values are bf16)
        *(short4v*)&dst[(s * 16 + (l & 15)) * PITCH + m0] = h;
    }
}

// ---------------- K2: per-(n,c) attention chain via bf16-split MFMA ----------
// Pt = K^T Q^T K ; A = soft_pd_max ; out = x + A V A^T
__global__ __launch_bounds__(256, 2) void k2_attn_mfma(
    const float* __restrict__ x, const float* __restrict__ Qi,
    const float* __restrict__ Ki, const float* __restrict__ Vi,
    float* __restrict__ out)
{
    // planes: 0 Qh->z4h  1 Ql->z4l  2 Kh->Z1h  3 Kl->Z1l  4 Vh  5 Vl  6 Kth->Ah  7 Ktl->Al
    __shared__ short planes[8][64 * PITCH];
    __shared__ float part[4][64];
    __shared__ float invs[64];
    __shared__ float red[4];

    const int t = threadIdx.x;
    const int l = t & 63, w = t >> 6;
    const size_t gbase = (size_t)blockIdx.x * 4096;

    stage_mat(Qi + gbase, planes[0], planes[1], t);
    stage_mat(Ki + gbase, planes[2], planes[3], t);
    stage_mat(Vi + gbase, planes[4], planes[5], t);
    __syncthreads();

    idtrans(planes[2], planes[6], w, l);   // Kt hi
    idtrans(planes[3], planes[7], w, l);   // Kt lo
    __syncthreads();

    f32x4 acc[4];

    // Z1 = pack(Q · Kt^T) = pack(Q·K) = (QK)^T = K^T Q^T   -> planes 2,3
    p3(planes[0], planes[1], planes[6], planes[7], w, l, acc);
    __syncthreads();                       // idtrans reads of planes 2,3 are done
    pack_store(acc, planes[2], planes[3], w, l);
    __syncthreads();

    // Pt = Z1 · Kt^T = K^T Q^T K   (in registers)
    p3(planes[2], planes[3], planes[6], planes[7], w, l, acc);

    // ---- soft_pd_max on Pt frags ----
    float mx = -1e30f;
#pragma unroll
    for (int ct = 0; ct < 4; ++ct)
#pragma unroll
        for (int r = 0; r < 4; ++r) mx = fmaxf(mx, acc[ct][r]);
#pragma unroll
    for (int off = 1; off < 64; off <<= 1) mx = fmaxf(mx, __shfl_xor(mx, off));
    if (l == 0) red[w] = mx;
    __syncthreads();
    mx = fmaxf(fmaxf(red[0], red[1]), fmaxf(red[2], red[3]));

    float e[4][4];
    float cs[4];
#pragma unroll
    for (int ct = 0; ct < 4; ++ct) {
        float s = 0.f;
#pragma unroll
        for (int r = 0; r < 4; ++r) {
            float ev = __expf(acc[ct][r] - mx);
            e[ct][r] = ev;
            s += ev;
        }
        cs[ct] = s;
    }
    // column sums of e(Pt) = row sums of e(P): reduce over lane groups (bits 4,5)
#pragma unroll
    for (int ct = 0; ct < 4; ++ct) {
        cs[ct] += __shfl_xor(cs[ct], 16);
        cs[ct] += __shfl_xor(cs[ct], 32);
    }
    if (l < 16) {
#pragma unroll
        for (int ct = 0; ct < 4; ++ct) part[w][ct * 16 + l] = cs[ct];
    }
    __syncthreads();
    if (t < 64) {
        float dia = part[0][t] + part[1][t] + part[2][t] + part[3][t];
        float tot = dia;
#pragma unroll
        for (int off = 1; off < 64; off <<= 1) tot += __shfl_xor(tot, off);
        dia = fmaxf(dia, tot / 100000.0f);
        dia = fmaxf(dia, 1e-5f);
        invs[t] = rsqrtf(dia);
    }
    __syncthreads();

    // At[m][n] = e[m][n]*inv[m]*inv[n]; pack-store -> A natural in planes 6,7 (Kt dead)
    {
        int m0 = w * 16 + (l >> 4) * 4;
        float ir[4] = {invs[m0], invs[m0 + 1], invs[m0 + 2], invs[m0 + 3]};
        int nb = l & 15;
#pragma unroll
        for (int ct = 0; ct < 4; ++ct) {
            float ic = invs[ct * 16 + nb];
            short4v h, lo;
#pragma unroll
            for (int r = 0; r < 4; ++r) {
                float v = e[ct][r] * ir[r] * ic;
                short hb = f2bf(v);
                h[r]  = hb;
                lo[r] = f2bf(v - bf2f(hb));
            }
            *(short4v*)&planes[6][(ct * 16 + nb) * PITCH + m0] = h;
            *(short4v*)&planes[7][(ct * 16 + nb) * PITCH + m0] = lo;
        }
    }
    __syncthreads();

    // z4 = pack(V · A^T) = A·V^T  -> planes 0,1 (Q dead)
    p3(planes[4], planes[5], planes[6], planes[7], w, l, acc);
    pack_store(acc, planes[0], planes[1], w, l);
    __syncthreads();

    // OUT = A · z4^T = A·V·A^T
    p3(planes[6], planes[7], planes[0], planes[1], w, l, acc);

    // residual + store
    {
        int m0 = w * 16 + (l >> 4) * 4;
        int nb = l & 15;
#pragma unroll
        for (int ct = 0; ct < 4; ++ct) {
            int n = ct * 16 + nb;
#pragma unroll
            for (int r = 0; r < 4; ++r) {
                size_t o = gbase + (size_t)(m0 + r) * 64 + n;
                out[o] = x[o] + acc[ct][r];
            }
        }
    }
}

// ---------------- launch -----------------------------------------------------
extern "C" void kernel_launch(void* const* d_in, const int* in_sizes, int n_in,
                              void* d_out, int out_size, void* d_ws, size_t ws_size,
                              hipStream_t stream) {
    const float* x  = (const float*)d_in[0];
    const float* wq = (const float*)d_in[1];
    const float* wk = (const float*)d_in[2];
    const float* wv = (const float*)d_in[3];
    float* out = (float*)d_out;

    float* invd = (float*)d_ws;                 // 1 MB
    float* K    = invd + 262144;                // 64 MB
    float* V    = K + 16777216;                 // 64 MB
    float* Q    = out;                          // reuse d_out as Q scratch

    k0_invdiag<<<1024, 256, 0, stream>>>(x, invd);
    k1_mix<<<4096, 256, 0, stream>>>(x, invd, wq, wk, wv, Q, K, V);
    k2_attn_mfma<<<4096, 256, 0, stream>>>(x, Q, K, V, out);
}

// Round 3
// 132.901 us; speedup vs baseline: 1.9126x; 1.3472x over previous
//
#include <hip/hip_runtime.h>

#define PITCH 72   // bf16 pitch for MFMA planes: 144 B rows, 16B-aligned

typedef __attribute__((ext_vector_type(8))) short short8v;
typedef __attribute__((ext_vector_type(4))) short short4v;
typedef __attribute__((ext_vector_type(4))) float f32x4;

// ---------------- bf16 split helpers -----------------------------------------
__device__ __forceinline__ short f2bf(float v) {
    unsigned u = __builtin_bit_cast(unsigned, v);
    unsigned r = (u + 0x7FFFu + ((u >> 16) & 1u)) >> 16;
    return (short)r;
}
__device__ __forceinline__ float bf2f(short s) {
    unsigned u = ((unsigned)(unsigned short)s) << 16;
    return __builtin_bit_cast(float, u);
}

#define MFMA(a, b, c) __builtin_amdgcn_mfma_f32_16x16x32_bf16(a, b, c, 0, 0, 0)

// A/B fragment from LDS plane (pitch 72)
__device__ __forceinline__ short8v ldfrag(const short* p, int rowtile, int kc, int l) {
    return *(const short8v*)&p[(rowtile * 16 + (l & 15)) * PITCH + kc * 32 + (l >> 4) * 8];
}
// fragment from global row-major [rows][64]
__device__ __forceinline__ short8v gfrag(const short* __restrict__ p, int rowtile, int kc, int l) {
    return *(const short8v*)&p[(rowtile * 16 + (l & 15)) * 64 + kc * 32 + (l >> 4) * 8];
}

// D = X·Y^T split-3; wave w owns D row-tile w, 4 col-tiles
__device__ __forceinline__ void p3(const short* xh, const short* xl,
                                   const short* yh, const short* yl,
                                   int w, int l, f32x4 (&acc)[4]) {
#pragma unroll
    for (int ct = 0; ct < 4; ++ct) acc[ct] = (f32x4){0.f, 0.f, 0.f, 0.f};
#pragma unroll
    for (int kc = 0; kc < 2; ++kc) {
        short8v aH = ldfrag(xh, w, kc, l);
        short8v aL = ldfrag(xl, w, kc, l);
#pragma unroll
        for (int ct = 0; ct < 4; ++ct) {
            short8v bH = ldfrag(yh, ct, kc, l);
            short8v bL = ldfrag(yl, ct, kc, l);
            acc[ct] = MFMA(aH, bH, acc[ct]);
            acc[ct] = MFMA(aH, bL, acc[ct]);
            acc[ct] = MFMA(aL, bH, acc[ct]);
        }
    }
}

// D = X·Y^T, X hi-only (2-term)
__device__ __forceinline__ void p2v(const short* xh,
                                    const short* yh, const short* yl,
                                    int w, int l, f32x4 (&acc)[4]) {
#pragma unroll
    for (int ct = 0; ct < 4; ++ct) acc[ct] = (f32x4){0.f, 0.f, 0.f, 0.f};
#pragma unroll
    for (int kc = 0; kc < 2; ++kc) {
        short8v aH = ldfrag(xh, w, kc, l);
#pragma unroll
        for (int ct = 0; ct < 4; ++ct) {
            short8v bH = ldfrag(yh, ct, kc, l);
            short8v bL = ldfrag(yl, ct, kc, l);
            acc[ct] = MFMA(aH, bH, acc[ct]);
            acc[ct] = MFMA(aH, bL, acc[ct]);
        }
    }
}

// pack-store D transposed with hi/lo split: z[n][m] = D[m][n]
__device__ __forceinline__ void pack_store(const f32x4 (&acc)[4],
                                           short* zh, short* zl, int w, int l) {
    int m0 = w * 16 + (l >> 4) * 4;
#pragma unroll
    for (int ct = 0; ct < 4; ++ct) {
        int n = ct * 16 + (l & 15);
        short4v h, lo;
#pragma unroll
        for (int r = 0; r < 4; ++r) {
            float v = acc[ct][r];
            short hb = f2bf(v);
            h[r]  = hb;
            lo[r] = f2bf(v - bf2f(hb));
        }
        *(short4v*)&zh[n * PITCH + m0] = h;
        *(short4v*)&zl[n * PITCH + m0] = lo;
    }
}

// exact transpose via identity-MFMA: dst[j][i] = src[i][j]
__device__ __forceinline__ void idtrans(const short* src, short* dst, int w, int l) {
    int m0 = w * 16 + (l >> 4) * 4;
#pragma unroll
    for (int s = 0; s < 4; ++s) {
        short8v a = ldfrag(src, w, s >> 1, l);
        short8v b;
#pragma unroll
        for (int j = 0; j < 8; ++j)
            b[j] = (8 * (l >> 4) + j == (l & 15) + 16 * (s & 1)) ? (short)0x3F80 : (short)0;
        f32x4 d = MFMA(a, b, ((f32x4){0.f, 0.f, 0.f, 0.f}));
        short4v h;
#pragma unroll
        for (int r = 0; r < 4; ++r) h[r] = f2bf(d[r]);   // exact (values are bf16)
        *(short4v*)&dst[(s * 16 + (l & 15)) * PITCH + m0] = h;
    }
}

// ---------------- K0: inv_diag ------------------------------------------------
__global__ __launch_bounds__(256) void k0_invdiag(const float* __restrict__ x,
                                                  float* __restrict__ invd) {
    int t = blockIdx.x * 256 + threadIdx.x;
    int nc = t >> 6, k = t & 63;
    float v = fabsf(x[(size_t)nc * 4096 + (size_t)k * 65]);
    invd[t] = rsqrtf(fmaxf(v, 1e-4f));
}

// ---------------- K0b: w3T[co][c] = concat(wq,wk,wv)^T, bf16 hi/lo ------------
__global__ __launch_bounds__(256) void k0b_w3(const float* __restrict__ wq,
                                              const float* __restrict__ wk,
                                              const float* __restrict__ wv,
                                              short* __restrict__ w3h,
                                              short* __restrict__ w3l) {
    int idx = blockIdx.x * 256 + threadIdx.x;   // [0, 12288)
    int co = idx >> 6, c = idx & 63;
    const float* w = (co < 64) ? wq : (co < 128) ? wk : wv;
    float v = w[c * 64 + (co & 63)];
    short h = f2bf(v);
    w3h[idx] = h;
    w3l[idx] = f2bf(v - bf2f(h));
}

// ---------------- K1: cov2cor + channel mixing via MFMA -----------------------
// Block (n,i): D[j][co] = sum_c cor[c][j] * W[c][co]  -> store [co][j] hi/lo
__global__ __launch_bounds__(256, 2) void k1_mix_mfma(
    const float* __restrict__ x, const float* __restrict__ invd,
    const short* __restrict__ w3h, const short* __restrict__ w3l,
    short* __restrict__ Qio,                       // d_out: per-nc 16KB slots (hi|lo)
    short* __restrict__ Kh, short* __restrict__ Kl, short* __restrict__ Vh)
{
    // phase1: ch,cl,cth,ctl (4 planes x 4608 shorts) ; phase2: zh/zl [192][72]
    __shared__ short buf[27648];
    short* ch  = buf;
    short* cl  = buf + 4608;
    short* cth = buf + 9216;
    short* ctl = buf + 13824;
    short* zh  = buf;            // phase 2 alias
    short* zl  = buf + 13824;

    const int b = blockIdx.x, n = b >> 6, i = b & 63;
    const int t = threadIdx.x, l = t & 63, w = t >> 6;
    const size_t nbase = (size_t)n * 64;

    // stage cor hi/lo planes [c][j]
#pragma unroll
    for (int rep = 0; rep < 4; ++rep) {
        int id = rep * 256 + t;                 // 1024 float4 chunks
        int c = id >> 4, j4 = (id & 15) * 4;
        float4 xv = *(const float4*)&x[((nbase + c) * 64 + i) * 64 + j4];
        float ii = invd[(nbase + c) * 64 + i];
        float4 jv = *(const float4*)&invd[(nbase + c) * 64 + j4];
        float vv[4] = {xv.x * ii * jv.x, xv.y * ii * jv.y,
                       xv.z * ii * jv.z, xv.w * ii * jv.w};
        short4v h, lo;
#pragma unroll
        for (int r = 0; r < 4; ++r) {
            float v = fminf(1.0f, fmaxf(-1.0f, vv[r]));
            short hb = f2bf(v);
            h[r]  = hb;
            lo[r] = f2bf(v - bf2f(hb));
        }
        *(short4v*)&ch[c * PITCH + j4] = h;
        *(short4v*)&cl[c * PITCH + j4] = lo;
    }
    __syncthreads();
    idtrans(ch, cth, w, l);
    idtrans(cl, ctl, w, l);
    __syncthreads();

    // wave w: co-tiles ct = 3w..3w+2, all 4 j-tiles; split-3
    f32x4 acc[4][3];
#pragma unroll
    for (int jt = 0; jt < 4; ++jt)
#pragma unroll
        for (int cc = 0; cc < 3; ++cc) acc[jt][cc] = (f32x4){0.f, 0.f, 0.f, 0.f};
#pragma unroll
    for (int kc = 0; kc < 2; ++kc) {
        short8v aH[4], aL[4];
#pragma unroll
        for (int jt = 0; jt < 4; ++jt) {
            aH[jt] = ldfrag(cth, jt, kc, l);
            aL[jt] = ldfrag(ctl, jt, kc, l);
        }
#pragma unroll
        for (int cc = 0; cc < 3; ++cc) {
            int ct = w * 3 + cc;
            short8v bH = gfrag(w3h, ct, kc, l);
            short8v bL = gfrag(w3l, ct, kc, l);
#pragma unroll
            for (int jt = 0; jt < 4; ++jt) {
                acc[jt][cc] = MFMA(aH[jt], bH, acc[jt][cc]);
                acc[jt][cc] = MFMA(aH[jt], bL, acc[jt][cc]);
                acc[jt][cc] = MFMA(aL[jt], bH, acc[jt][cc]);
            }
        }
    }
    __syncthreads();   // all reads of cth/ctl complete; alias buf as z

    // pack transposed: z[co][j] hi/lo
    {
        int m0 = (l >> 4) * 4;
        int nb = l & 15;
#pragma unroll
        for (int cc = 0; cc < 3; ++cc) {
            int nrow = (w * 3 + cc) * 16 + nb;
#pragma unroll
            for (int jt = 0; jt < 4; ++jt) {
                short4v h, lo;
#pragma unroll
                for (int r = 0; r < 4; ++r) {
                    float v = acc[jt][cc][r];
                    short hb = f2bf(v);
                    h[r]  = hb;
                    lo[r] = f2bf(v - bf2f(hb));
                }
                *(short4v*)&zh[nrow * PITCH + jt * 16 + m0] = h;
                *(short4v*)&zl[nrow * PITCH + jt * 16 + m0] = lo;
            }
        }
    }
    __syncthreads();

    // copy to global. hi: all 192 rows; lo: rows 0..127 (Q,K only)
#pragma unroll
    for (int rep = 0; rep < 12; ++rep) {
        int id = rep * 256 + t;                 // 3072 chunks
        int co3 = id >> 4, j4 = (id & 15) * 4;
        short4v v = *(short4v*)&zh[co3 * PITCH + j4];
        if (co3 < 64) {
            size_t nc = nbase + co3;
            *(short4v*)&Qio[nc * 8192 + (size_t)i * 64 + j4] = v;
        } else if (co3 < 128) {
            size_t nc = nbase + (co3 - 64);
            *(short4v*)&Kh[nc * 4096 + (size_t)i * 64 + j4] = v;
        } else {
            size_t nc = nbase + (co3 - 128);
            *(short4v*)&Vh[nc * 4096 + (size_t)i * 64 + j4] = v;
        }
    }
#pragma unroll
    for (int rep = 0; rep < 8; ++rep) {
        int id = rep * 256 + t;                 // 2048 chunks (rows 0..127)
        int co3 = id >> 4, j4 = (id & 15) * 4;
        short4v v = *(short4v*)&zl[co3 * PITCH + j4];
        if (co3 < 64) {
            size_t nc = nbase + co3;
            *(short4v*)&Qio[nc * 8192 + 4096 + (size_t)i * 64 + j4] = v;
        } else {
            size_t nc = nbase + (co3 - 64);
            *(short4v*)&Kl[nc * 4096 + (size_t)i * 64 + j4] = v;
        }
    }
}

// ---------------- K2: per-(n,c) attention chain (split-bf16 MFMA) -------------
__global__ __launch_bounds__(256, 2) void k2_attn_mfma(
    const float* __restrict__ x,
    const short* __restrict__ Qio,
    const short* __restrict__ Kh, const short* __restrict__ Kl,
    const short* __restrict__ Vh,
    float* __restrict__ out)
{
    // planes: 0 Qh->z4h  1 Ql->z4l  2 Kh->Z1h  3 Kl->Z1l  4 Vh  5 Kth->Ah  6 Ktl->Al
    __shared__ short planes[7][64 * PITCH];
    __shared__ float part[4][64];
    __shared__ float invs[64];
    __shared__ float red[4];

    const int t = threadIdx.x, l = t & 63, w = t >> 6;
    const int nc = blockIdx.x;
    const size_t gbase = (size_t)nc * 4096;

    const short* qh = Qio + (size_t)nc * 8192;
    const short* ql = qh + 4096;
    const short* kh = Kh + gbase;
    const short* kl = Kl + gbase;
    const short* vh = Vh + gbase;
#pragma unroll
    for (int rep = 0; rep < 4; ++rep) {
        int id = rep * 256 + t;
        int r = id >> 4, c4 = (id & 15) * 4;
        *(short4v*)&planes[0][r * PITCH + c4] = *(const short4v*)&qh[r * 64 + c4];
        *(short4v*)&planes[1][r * PITCH + c4] = *(const short4v*)&ql[r * 64 + c4];
        *(short4v*)&planes[2][r * PITCH + c4] = *(const short4v*)&kh[r * 64 + c4];
        *(short4v*)&planes[3][r * PITCH + c4] = *(const short4v*)&kl[r * 64 + c4];
        *(short4v*)&planes[4][r * PITCH + c4] = *(const short4v*)&vh[r * 64 + c4];
    }
    __syncthreads();

    idtrans(planes[2], planes[5], w, l);   // Kt hi
    idtrans(planes[3], planes[6], w, l);   // Kt lo
    __syncthreads();

    f32x4 acc[4];

    // Z1 = pack(Q · Kt^T) -> planes 2,3
    p3(planes[0], planes[1], planes[5], planes[6], w, l, acc);
    __syncthreads();
    pack_store(acc, planes[2], planes[3], w, l);
    __syncthreads();

    // Pt = Z1 · Kt^T (in registers)
    p3(planes[2], planes[3], planes[5], planes[6], w, l, acc);

    // ---- soft_pd_max ----
    float mx = -1e30f;
#pragma unroll
    for (int ct = 0; ct < 4; ++ct)
#pragma unroll
        for (int r = 0; r < 4; ++r) mx = fmaxf(mx, acc[ct][r]);
#pragma unroll
    for (int off = 1; off < 64; off <<= 1) mx = fmaxf(mx, __shfl_xor(mx, off));
    if (l == 0) red[w] = mx;
    __syncthreads();
    mx = fmaxf(fmaxf(red[0], red[1]), fmaxf(red[2], red[3]));

    float e[4][4];
    float cs[4];
#pragma unroll
    for (int ct = 0; ct < 4; ++ct) {
        float s = 0.f;
#pragma unroll
        for (int r = 0; r < 4; ++r) {
            float ev = __expf(acc[ct][r] - mx);
            e[ct][r] = ev;
            s += ev;
        }
        cs[ct] = s;
    }
#pragma unroll
    for (int ct = 0; ct < 4; ++ct) {
        cs[ct] += __shfl_xor(cs[ct], 16);
        cs[ct] += __shfl_xor(cs[ct], 32);
    }
    if (l < 16) {
#pragma unroll
        for (int ct = 0; ct < 4; ++ct) part[w][ct * 16 + l] = cs[ct];
    }
    __syncthreads();
    if (t < 64) {
        float dia = part[0][t] + part[1][t] + part[2][t] + part[3][t];
        float tot = dia;
#pragma unroll
        for (int off = 1; off < 64; off <<= 1) tot += __shfl_xor(tot, off);
        dia = fmaxf(dia, tot / 100000.0f);
        dia = fmaxf(dia, 1e-5f);
        invs[t] = rsqrtf(dia);
    }
    __syncthreads();

    // A[m][n] = e*inv*inv -> planes 5,6 (Kt dead)
    {
        int m0 = w * 16 + (l >> 4) * 4;
        float ir[4] = {invs[m0], invs[m0 + 1], invs[m0 + 2], invs[m0 + 3]};
        int nb = l & 15;
#pragma unroll
        for (int ct = 0; ct < 4; ++ct) {
            float ic = invs[ct * 16 + nb];
            short4v h, lo;
#pragma unroll
            for (int r = 0; r < 4; ++r) {
                float v = e[ct][r] * ir[r] * ic;
                short hb = f2bf(v);
                h[r]  = hb;
                lo[r] = f2bf(v - bf2f(hb));
            }
            *(short4v*)&planes[5][(ct * 16 + nb) * PITCH + m0] = h;
            *(short4v*)&planes[6][(ct * 16 + nb) * PITCH + m0] = lo;
        }
    }
    __syncthreads();

    // z4 = pack(Vh · A^T) -> planes 0,1 (Q dead)
    p2v(planes[4], planes[5], planes[6], w, l, acc);
    pack_store(acc, planes[0], planes[1], w, l);
    __syncthreads();

    // OUT = A · z4^T = A V A^T
    p3(planes[5], planes[6], planes[0], planes[1], w, l, acc);

    // residual + store
    {
        int m0 = w * 16 + (l >> 4) * 4;
        int nb = l & 15;
#pragma unroll
        for (int ct = 0; ct < 4; ++ct) {
            int n = ct * 16 + nb;
#pragma unroll
            for (int r = 0; r < 4; ++r) {
                size_t o = gbase + (size_t)(m0 + r) * 64 + n;
                out[o] = x[o] + acc[ct][r];
            }
        }
    }
}

// ---------------- launch -----------------------------------------------------
extern "C" void kernel_launch(void* const* d_in, const int* in_sizes, int n_in,
                              void* d_out, int out_size, void* d_ws, size_t ws_size,
                              hipStream_t stream) {
    const float* x  = (const float*)d_in[0];
    const float* wq = (const float*)d_in[1];
    const float* wk = (const float*)d_in[2];
    const float* wv = (const float*)d_in[3];
    float* out = (float*)d_out;

    char* wsb = (char*)d_ws;
    float* invd = (float*)wsb;                       // 1 MB
    short* w3h  = (short*)(wsb + (1 << 20));         // 24 KB
    short* w3l  = w3h + 12288;                       // 24 KB
    short* Kh   = (short*)(wsb + (2 << 20));         // 32 MB
    short* Kl   = Kh + 16777216;                     // 32 MB
    short* Vh   = Kl + 16777216;                     // 32 MB
    short* Qio  = (short*)d_out;                     // per-nc 16KB (hi|lo) slots

    k0_invdiag<<<1024, 256, 0, stream>>>(x, invd);
    k0b_w3<<<48, 256, 0, stream>>>(wq, wk, wv, w3h, w3l);
    k1_mix_mfma<<<4096, 256, 0, stream>>>(x, invd, w3h, w3l, Qio, Kh, Kl, Vh);
    k2_attn_mfma<<<4096, 256, 0, stream>>>(x, Qio, Kh, Kl, Vh, out);
}

// Round 4
// 117.677 us; speedup vs baseline: 2.1600x; 1.1294x over previous
//
#include <hip/hip_runtime.h>

#define PITCH 72   // bf16 pitch for MFMA planes: 144 B rows, 16B-aligned

typedef __attribute__((ext_vector_type(8))) short short8v;
typedef __attribute__((ext_vector_type(4))) short short4v;
typedef __attribute__((ext_vector_type(4))) float f32x4;

// ---------------- bf16 split helpers -----------------------------------------
__device__ __forceinline__ short f2bf(float v) {
    unsigned u = __builtin_bit_cast(unsigned, v);
    unsigned r = (u + 0x7FFFu + ((u >> 16) & 1u)) >> 16;
    return (short)r;
}
__device__ __forceinline__ float bf2f(short s) {
    unsigned u = ((unsigned)(unsigned short)s) << 16;
    return __builtin_bit_cast(float, u);
}

#define MFMA(a, b, c) __builtin_amdgcn_mfma_f32_16x16x32_bf16(a, b, c, 0, 0, 0)

// A/B fragment from LDS plane (pitch 72)
__device__ __forceinline__ short8v ldfrag(const short* p, int rowtile, int kc, int l) {
    return *(const short8v*)&p[(rowtile * 16 + (l & 15)) * PITCH + kc * 32 + (l >> 4) * 8];
}
// fragment from global row-major [rows][64]
__device__ __forceinline__ short8v gfrag(const short* __restrict__ p, int rowtile, int kc, int l) {
    return *(const short8v*)&p[(rowtile * 16 + (l & 15)) * 64 + kc * 32 + (l >> 4) * 8];
}

// D = X·Y^T split-3; wave w owns D row-tile w, 4 col-tiles
__device__ __forceinline__ void p3(const short* xh, const short* xl,
                                   const short* yh, const short* yl,
                                   int w, int l, f32x4 (&acc)[4]) {
#pragma unroll
    for (int ct = 0; ct < 4; ++ct) acc[ct] = (f32x4){0.f, 0.f, 0.f, 0.f};
#pragma unroll
    for (int kc = 0; kc < 2; ++kc) {
        short8v aH = ldfrag(xh, w, kc, l);
        short8v aL = ldfrag(xl, w, kc, l);
#pragma unroll
        for (int ct = 0; ct < 4; ++ct) {
            short8v bH = ldfrag(yh, ct, kc, l);
            short8v bL = ldfrag(yl, ct, kc, l);
            acc[ct] = MFMA(aH, bH, acc[ct]);
            acc[ct] = MFMA(aH, bL, acc[ct]);
            acc[ct] = MFMA(aL, bH, acc[ct]);
        }
    }
}

// D = X·Y^T, X hi-only from GLOBAL row-major [64][64]
__device__ __forceinline__ void p2v_g(const short* __restrict__ xg,
                                      const short* yh, const short* yl,
                                      int w, int l, f32x4 (&acc)[4]) {
#pragma unroll
    for (int ct = 0; ct < 4; ++ct) acc[ct] = (f32x4){0.f, 0.f, 0.f, 0.f};
#pragma unroll
    for (int kc = 0; kc < 2; ++kc) {
        short8v aH = gfrag(xg, w, kc, l);
#pragma unroll
        for (int ct = 0; ct < 4; ++ct) {
            short8v bH = ldfrag(yh, ct, kc, l);
            short8v bL = ldfrag(yl, ct, kc, l);
            acc[ct] = MFMA(aH, bH, acc[ct]);
            acc[ct] = MFMA(aH, bL, acc[ct]);
        }
    }
}

// pack-store D transposed with hi/lo split: z[n][m] = D[m][n]
__device__ __forceinline__ void pack_store(const f32x4 (&acc)[4],
                                           short* zh, short* zl, int w, int l) {
    int m0 = w * 16 + (l >> 4) * 4;
#pragma unroll
    for (int ct = 0; ct < 4; ++ct) {
        int n = ct * 16 + (l & 15);
        short4v h, lo;
#pragma unroll
        for (int r = 0; r < 4; ++r) {
            float v = acc[ct][r];
            short hb = f2bf(v);
            h[r]  = hb;
            lo[r] = f2bf(v - bf2f(hb));
        }
        *(short4v*)&zh[n * PITCH + m0] = h;
        *(short4v*)&zl[n * PITCH + m0] = lo;
    }
}

// in-place exact transpose of TWO planes via identity-MFMA.
// Reads all needed frags to regs, barriers, writes back. Contains 1 barrier.
__device__ __forceinline__ void idtrans_ip2(short* pa, short* pb, int w, int l) {
    short8v a0 = ldfrag(pa, w, 0, l);
    short8v a1 = ldfrag(pa, w, 1, l);
    short8v b0 = ldfrag(pb, w, 0, l);
    short8v b1 = ldfrag(pb, w, 1, l);
    short8v I0, I1;
#pragma unroll
    for (int j = 0; j < 8; ++j) {
        int bit = 8 * (l >> 4) + j;
        I0[j] = (bit == (l & 15))      ? (short)0x3F80 : (short)0;
        I1[j] = (bit == (l & 15) + 16) ? (short)0x3F80 : (short)0;
    }
    __syncthreads();
    int m0 = w * 16 + (l >> 4) * 4;
    const f32x4 z4 = {0.f, 0.f, 0.f, 0.f};
#pragma unroll
    for (int s = 0; s < 4; ++s) {
        short8v a = (s < 2) ? ((s & 1) ? a0 : a0) : a1;   // kc = s>>1
        // note: b operand selects dst row block via s&1
        f32x4 d = MFMA((s >> 1) ? a1 : a0, (s & 1) ? I1 : I0, z4);
        f32x4 e = MFMA((s >> 1) ? b1 : b0, (s & 1) ? I1 : I0, z4);
        short4v ha, hb2;
#pragma unroll
        for (int r = 0; r < 4; ++r) { ha[r] = f2bf(d[r]); hb2[r] = f2bf(e[r]); }
        int drow = s * 16 + (l & 15);
        *(short4v*)&pa[drow * PITCH + m0] = ha;
        *(short4v*)&pb[drow * PITCH + m0] = hb2;
        (void)a;
    }
}

// ---------------- K0: inv_diag ------------------------------------------------
__global__ __launch_bounds__(256) void k0_invdiag(const float* __restrict__ x,
                                                  float* __restrict__ invd) {
    int t = blockIdx.x * 256 + threadIdx.x;
    int nc = t >> 6, k = t & 63;
    float v = fabsf(x[(size_t)nc * 4096 + (size_t)k * 65]);
    invd[t] = rsqrtf(fmaxf(v, 1e-4f));
}

// ---------------- K0b: w3T[co][c] = concat(wq,wk,wv)^T, bf16 hi/lo ------------
__global__ __launch_bounds__(256) void k0b_w3(const float* __restrict__ wq,
                                              const float* __restrict__ wk,
                                              const float* __restrict__ wv,
                                              short* __restrict__ w3h,
                                              short* __restrict__ w3l) {
    int idx = blockIdx.x * 256 + threadIdx.x;   // [0, 12288)
    int co = idx >> 6, c = idx & 63;
    const float* w = (co < 64) ? wq : (co < 128) ? wk : wv;
    float v = w[c * 64 + (co & 63)];
    short h = f2bf(v);
    w3h[idx] = h;
    w3l[idx] = f2bf(v - bf2f(h));
}

// ---------------- K1: cov2cor + channel mixing via MFMA -----------------------
// Block (n,i): D[j][co] = sum_c cor[c][j] * W[c][co]  -> store [co][j] hi/lo
__global__ __launch_bounds__(256, 4) void k1_mix_mfma(
    const float* __restrict__ x, const float* __restrict__ invd,
    const short* __restrict__ w3h, const short* __restrict__ w3l,
    short* __restrict__ Qio,                       // d_out: per-nc 16KB slots (hi|lo)
    short* __restrict__ Kh, short* __restrict__ Kl, short* __restrict__ Vh)
{
    // phase1: ch,cl [64][72] each (aliased at start of zbuf); phase2: z [192][72]
    __shared__ __align__(16) short zbuf[13824];    // 27648 B
    short* ch = zbuf;
    short* cl = zbuf + 4608;

    const int b = blockIdx.x, n = b >> 6, i = b & 63;
    const int t = threadIdx.x, l = t & 63, w = t >> 6;
    const size_t nbase = (size_t)n * 64;

    // stage cor hi/lo planes [c][j]
#pragma unroll
    for (int rep = 0; rep < 4; ++rep) {
        int id = rep * 256 + t;                 // 1024 float4 chunks
        int c = id >> 4, j4 = (id & 15) * 4;
        float4 xv = *(const float4*)&x[((nbase + c) * 64 + i) * 64 + j4];
        float ii = invd[(nbase + c) * 64 + i];
        float4 jv = *(const float4*)&invd[(nbase + c) * 64 + j4];
        float vv[4] = {xv.x * ii * jv.x, xv.y * ii * jv.y,
                       xv.z * ii * jv.z, xv.w * ii * jv.w};
        short4v h, lo;
#pragma unroll
        for (int r = 0; r < 4; ++r) {
            float v = fminf(1.0f, fmaxf(-1.0f, vv[r]));
            short hb = f2bf(v);
            h[r]  = hb;
            lo[r] = f2bf(v - bf2f(hb));
        }
        *(short4v*)&ch[c * PITCH + j4] = h;
        *(short4v*)&cl[c * PITCH + j4] = lo;
    }
    __syncthreads();
    idtrans_ip2(ch, cl, w, l);     // cor -> corT in place (1 internal barrier)
    __syncthreads();

    // wave w: co-tiles ct = 3w..3w+2, all 4 j-tiles; split-3
    f32x4 acc[4][3];
#pragma unroll
    for (int jt = 0; jt < 4; ++jt)
#pragma unroll
        for (int cc = 0; cc < 3; ++cc) acc[jt][cc] = (f32x4){0.f, 0.f, 0.f, 0.f};
#pragma unroll
    for (int kc = 0; kc < 2; ++kc) {
        short8v aH[4], aL[4];
#pragma unroll
        for (int jt = 0; jt < 4; ++jt) {
            aH[jt] = ldfrag(ch, jt, kc, l);
            aL[jt] = ldfrag(cl, jt, kc, l);
        }
#pragma unroll
        for (int cc = 0; cc < 3; ++cc) {
            int ct = w * 3 + cc;
            short8v bH = gfrag(w3h, ct, kc, l);
            short8v bL = gfrag(w3l, ct, kc, l);
#pragma unroll
            for (int jt = 0; jt < 4; ++jt) {
                acc[jt][cc] = MFMA(aH[jt], bH, acc[jt][cc]);
                acc[jt][cc] = MFMA(aH[jt], bL, acc[jt][cc]);
                acc[jt][cc] = MFMA(aL[jt], bH, acc[jt][cc]);
            }
        }
    }
    __syncthreads();   // all reads of ch/cl done; alias zbuf as z

    // ---- pass A: pack + copy HI (all 192 rows) ----
    {
        int m0 = (l >> 4) * 4, nb = l & 15;
#pragma unroll
        for (int cc = 0; cc < 3; ++cc) {
            int nrow = (w * 3 + cc) * 16 + nb;
#pragma unroll
            for (int jt = 0; jt < 4; ++jt) {
                short4v h;
#pragma unroll
                for (int r = 0; r < 4; ++r) h[r] = f2bf(acc[jt][cc][r]);
                *(short4v*)&zbuf[nrow * PITCH + jt * 16 + m0] = h;
            }
        }
    }
    __syncthreads();
#pragma unroll
    for (int rep = 0; rep < 12; ++rep) {
        int id = rep * 256 + t;                 // 3072 chunks
        int co3 = id >> 4, j4 = (id & 15) * 4;
        short4v v = *(short4v*)&zbuf[co3 * PITCH + j4];
        if (co3 < 64) {
            size_t nc = nbase + co3;
            *(short4v*)&Qio[nc * 8192 + (size_t)i * 64 + j4] = v;
        } else if (co3 < 128) {
            size_t nc = nbase + (co3 - 64);
            *(short4v*)&Kh[nc * 4096 + (size_t)i * 64 + j4] = v;
        } else {
            size_t nc = nbase + (co3 - 128);
            *(short4v*)&Vh[nc * 4096 + (size_t)i * 64 + j4] = v;
        }
    }
    __syncthreads();

    // ---- pass B: pack + copy LO (rows 0..127 = Q,K only) ----
    {
        int m0 = (l >> 4) * 4, nb = l & 15;
#pragma unroll
        for (int cc = 0; cc < 3; ++cc) {
            int r16 = w * 3 + cc;
            if (r16 < 8) {
                int nrow = r16 * 16 + nb;
#pragma unroll
                for (int jt = 0; jt < 4; ++jt) {
                    short4v lo;
#pragma unroll
                    for (int r = 0; r < 4; ++r) {
                        float v = acc[jt][cc][r];
                        lo[r] = f2bf(v - bf2f(f2bf(v)));
                    }
                    *(short4v*)&zbuf[nrow * PITCH + jt * 16 + m0] = lo;
                }
            }
        }
    }
    __syncthreads();
#pragma unroll
    for (int rep = 0; rep < 8; ++rep) {
        int id = rep * 256 + t;                 // 2048 chunks (rows 0..127)
        int co3 = id >> 4, j4 = (id & 15) * 4;
        short4v v = *(short4v*)&zbuf[co3 * PITCH + j4];
        if (co3 < 64) {
            size_t nc = nbase + co3;
            *(short4v*)&Qio[nc * 8192 + 4096 + (size_t)i * 64 + j4] = v;
        } else {
            size_t nc = nbase + (co3 - 64);
            *(short4v*)&Kl[nc * 4096 + (size_t)i * 64 + j4] = v;
        }
    }
}

// ---------------- K2: per-(n,c) attention chain (split-bf16 MFMA) -------------
__global__ __launch_bounds__(256, 4) void k2_attn_mfma(
    const float* __restrict__ x,
    const short* __restrict__ Qio,
    const short* __restrict__ Kh, const short* __restrict__ Kl,
    const short* __restrict__ Vh,
    float* __restrict__ out)
{
    // P0 Qh->Z1h->z4h ; P1 Ql->Z1l->z4l ; P2 Kh->Kth->Ah ; P3 Kl->Ktl->Al
    __shared__ __align__(16) short planes[4][4608];
    __shared__ float part[4][64];
    __shared__ float invs[64];
    __shared__ float red[4];

    const int t = threadIdx.x, l = t & 63, w = t >> 6;
    const int nc = blockIdx.x;
    const size_t gbase = (size_t)nc * 4096;

    const short* qh = Qio + (size_t)nc * 8192;
    const short* ql = qh + 4096;
    const short* kh = Kh + gbase;
    const short* kl = Kl + gbase;
    const short* vh = Vh + gbase;
#pragma unroll
    for (int rep = 0; rep < 4; ++rep) {
        int id = rep * 256 + t;
        int r = id >> 4, c4 = (id & 15) * 4;
        *(short4v*)&planes[0][r * PITCH + c4] = *(const short4v*)&qh[r * 64 + c4];
        *(short4v*)&planes[1][r * PITCH + c4] = *(const short4v*)&ql[r * 64 + c4];
        *(short4v*)&planes[2][r * PITCH + c4] = *(const short4v*)&kh[r * 64 + c4];
        *(short4v*)&planes[3][r * PITCH + c4] = *(const short4v*)&kl[r * 64 + c4];
    }
    __syncthreads();

    idtrans_ip2(planes[2], planes[3], w, l);   // K -> Kt in place
    __syncthreads();

    f32x4 acc[4];

    // Z1 = Q · Kt^T  (pack -> P0,P1 after barrier)
    p3(planes[0], planes[1], planes[2], planes[3], w, l, acc);
    __syncthreads();
    pack_store(acc, planes[0], planes[1], w, l);
    __syncthreads();

    // Pt = Z1 · Kt^T (in registers)
    p3(planes[0], planes[1], planes[2], planes[3], w, l, acc);

    // ---- soft_pd_max ----
    float mx = -1e30f;
#pragma unroll
    for (int ct = 0; ct < 4; ++ct)
#pragma unroll
        for (int r = 0; r < 4; ++r) mx = fmaxf(mx, acc[ct][r]);
#pragma unroll
    for (int off = 1; off < 64; off <<= 1) mx = fmaxf(mx, __shfl_xor(mx, off));
    if (l == 0) red[w] = mx;
    __syncthreads();
    mx = fmaxf(fmaxf(red[0], red[1]), fmaxf(red[2], red[3]));

    float e[4][4];
    float cs[4];
#pragma unroll
    for (int ct = 0; ct < 4; ++ct) {
        float s = 0.f;
#pragma unroll
        for (int r = 0; r < 4; ++r) {
            float ev = __expf(acc[ct][r] - mx);
            e[ct][r] = ev;
            s += ev;
        }
        cs[ct] = s;
    }
#pragma unroll
    for (int ct = 0; ct < 4; ++ct) {
        cs[ct] += __shfl_xor(cs[ct], 16);
        cs[ct] += __shfl_xor(cs[ct], 32);
    }
    if (l < 16) {
#pragma unroll
        for (int ct = 0; ct < 4; ++ct) part[w][ct * 16 + l] = cs[ct];
    }
    __syncthreads();
    if (t < 64) {
        float dia = part[0][t] + part[1][t] + part[2][t] + part[3][t];
        float tot = dia;
#pragma unroll
        for (int off = 1; off < 64; off <<= 1) tot += __shfl_xor(tot, off);
        dia = fmaxf(dia, tot / 100000.0f);
        dia = fmaxf(dia, 1e-5f);
        invs[t] = rsqrtf(dia);
    }
    __syncthreads();

    // A[m][n] = e*inv*inv -> P2,P3 (Kt dead; softmax barriers separate Pt reads)
    {
        int m0 = w * 16 + (l >> 4) * 4;
        float ir[4] = {invs[m0], invs[m0 + 1], invs[m0 + 2], invs[m0 + 3]};
        int nb = l & 15;
#pragma unroll
        for (int ct = 0; ct < 4; ++ct) {
            float ic = invs[ct * 16 + nb];
            short4v h, lo;
#pragma unroll
            for (int r = 0; r < 4; ++r) {
                float v = e[ct][r] * ir[r] * ic;
                short hb = f2bf(v);
                h[r]  = hb;
                lo[r] = f2bf(v - bf2f(hb));
            }
            *(short4v*)&planes[2][(ct * 16 + nb) * PITCH + m0] = h;
            *(short4v*)&planes[3][(ct * 16 + nb) * PITCH + m0] = lo;
        }
    }
    __syncthreads();

    // z4 = V(global) · A^T  -> pack into P0,P1 (dead since Pt + barriers)
    p2v_g(vh, planes[2], planes[3], w, l, acc);
    pack_store(acc, planes[0], planes[1], w, l);
    __syncthreads();

    // OUT = A · z4^T = A V A^T
    p3(planes[2], planes[3], planes[0], planes[1], w, l, acc);
    __syncthreads();   // all reads of P0,P1 done; alias as f32 out-stage

    // stage out tile f32 [64][68] over P0,P1 then vectorized residual+store
    {
        float* ofs = (float*)&planes[0][0];
        int m0 = w * 16 + (l >> 4) * 4;
        int nb = l & 15;
#pragma unroll
        for (int ct = 0; ct < 4; ++ct)
#pragma unroll
            for (int r = 0; r < 4; ++r)
                ofs[(m0 + r) * 68 + ct * 16 + nb] = acc[ct][r];
    }
    __syncthreads();
    {
        const float* ofs = (const float*)&planes[0][0];
#pragma unroll
        for (int rep = 0; rep < 4; ++rep) {
            int id = rep * 256 + t;
            int row = id >> 4, c4 = (id & 15) * 4;
            float4 v  = *(const float4*)&ofs[row * 68 + c4];
            float4 xv = *(const float4*)&x[gbase + (size_t)row * 64 + c4];
            *(float4*)&out[gbase + (size_t)row * 64 + c4] =
                make_float4(xv.x + v.x, xv.y + v.y, xv.z + v.z, xv.w + v.w);
        }
    }
}

// ---------------- launch -----------------------------------------------------
extern "C" void kernel_launch(void* const* d_in, const int* in_sizes, int n_in,
                              void* d_out, int out_size, void* d_ws, size_t ws_size,
                              hipStream_t stream) {
    const float* x  = (const float*)d_in[0];
    const float* wq = (const float*)d_in[1];
    const float* wk = (const float*)d_in[2];
    const float* wv = (const float*)d_in[3];
    float* out = (float*)d_out;

    char* wsb = (char*)d_ws;
    float* invd = (float*)wsb;                       // 1 MB
    short* w3h  = (short*)(wsb + (1 << 20));         // 24 KB
    short* w3l  = w3h + 12288;                       // 24 KB
    short* Kh   = (short*)(wsb + (2 << 20));         // 32 MB
    short* Kl   = Kh + 16777216;                     // 32 MB
    short* Vh   = Kl + 16777216;                     // 32 MB
    short* Qio  = (short*)d_out;                     // per-nc 16KB (hi|lo) slots

    k0_invdiag<<<1024, 256, 0, stream>>>(x, invd);
    k0b_w3<<<48, 256, 0, stream>>>(wq, wk, wv, w3h, w3l);
    k1_mix_mfma<<<4096, 256, 0, stream>>>(x, invd, w3h, w3l, Qio, Kh, Kl, Vh);
    k2_attn_mfma<<<4096, 256, 0, stream>>>(x, Qio, Kh, Kl, Vh, out);
}